// Round 7
// baseline (664.214 us; speedup 1.0000x reference)
//
#include <hip/hip_runtime.h>

#define TT 2000
#define BB 64
#define HH 256
#define BH (BB*HH)
#define CH 16           // chunk = 16 time steps
#define NCH (TT/CH)     // 125 chunks

typedef __attribute__((ext_vector_type(4))) float f4raw;

__device__ __forceinline__ float clip01(float x) { return fminf(fmaxf(x, 0.0f), 1.0f); }

// ---------------- transpose both weight matrices (256KB each) ----------------
__global__ void transpose2(const float* __restrict__ w_in, const float* __restrict__ w_rec,
                           float* __restrict__ w_inT, float* __restrict__ w_recT) {
    int idx = blockIdx.x * 256 + threadIdx.x;   // 65536 per matrix
    int k = idx >> 8, h = idx & 255;
    w_inT[idx]  = w_in[h * HH + k];             // w_inT[k][h] = w_in[h][k]
    w_recT[idx] = w_rec[h * HH + k];
}

// ---------------- f32 GEMM: xw[n,h] = sum_k X[n,k] * w_inT[k,h] ----------------
#define BM 128
#define BN 128
#define BK 32
__global__ __launch_bounds__(256) void gemm_xw(const float* __restrict__ X,
                                               const float* __restrict__ WT,
                                               float* __restrict__ OutXW) {
    __shared__ __align__(16) float XsT[BK][BM + 4];   // transposed: [k][row]
    __shared__ __align__(16) float Ws[BK][BN + 4];    // [k][col]
    int tid = threadIdx.x;
    int n0 = blockIdx.x * BM;
    int h0 = blockIdx.y * BN;
    int ty = tid >> 4, tx = tid & 15;
    float acc[8][8] = {};

    for (int kc = 0; kc < HH; kc += BK) {
        {
            int r = tid & 127, kseg = (tid >> 7) * 16;
            const float* src = X + (size_t)(n0 + r) * HH + kc + kseg;
#pragma unroll
            for (int q = 0; q < 4; q++) {
                float4 xv = *(const float4*)(src + q * 4);
                XsT[kseg + q * 4 + 0][r] = xv.x;
                XsT[kseg + q * 4 + 1][r] = xv.y;
                XsT[kseg + q * 4 + 2][r] = xv.z;
                XsT[kseg + q * 4 + 3][r] = xv.w;
            }
        }
        {
            int krow = tid >> 3, cs = (tid & 7) * 16;
            const float* src = WT + (size_t)(kc + krow) * HH + h0 + cs;
#pragma unroll
            for (int q = 0; q < 4; q++) {
                float4 wv = *(const float4*)(src + q * 4);
                *(float4*)&Ws[krow][cs + q * 4] = wv;
            }
        }
        __syncthreads();
#pragma unroll 4
        for (int kk = 0; kk < BK; kk++) {
            float4 a0 = *(const float4*)&XsT[kk][ty * 8];
            float4 a1 = *(const float4*)&XsT[kk][ty * 8 + 4];
            float4 b0 = *(const float4*)&Ws[kk][tx * 8];
            float4 b1 = *(const float4*)&Ws[kk][tx * 8 + 4];
            float a[8] = {a0.x, a0.y, a0.z, a0.w, a1.x, a1.y, a1.z, a1.w};
            float bb[8] = {b0.x, b0.y, b0.z, b0.w, b1.x, b1.y, b1.z, b1.w};
#pragma unroll
            for (int r = 0; r < 8; r++)
#pragma unroll
                for (int c = 0; c < 8; c++)
                    acc[r][c] += a[r] * bb[c];
        }
        __syncthreads();
    }
#pragma unroll
    for (int r = 0; r < 8; r++) {
        int n = n0 + ty * 8 + r;
        int b = n / TT;
        int t = n - b * TT;
        float* dst = OutXW + ((size_t)t * BB + b) * HH + h0 + tx * 8;
        float4 s0 = {acc[r][0], acc[r][1], acc[r][2], acc[r][3]};
        float4 s1 = {acc[r][4], acc[r][5], acc[r][6], acc[r][7]};
        *(float4*)dst = s0;
        *(float4*)(dst + 4) = s1;
    }
}

// ---------------- sequential LIF scan: producer/consumer wave pair per batch ----------------
// Ownership: lane l owns neurons h = 4l..4l+3 -> one dwordx4 per spike gather,
// one float4 NT store per step. Spike-sum order is ascending h (= np's dense
// ascending-k sum, since adding exact zeros is an fp identity).
// Deferred gather: step t's spike loads issued at end of step t (batched, they
// pipeline), accumulated at BOTTOM of step t+1 -> one L2 latency hidden under
// step t+1's dynamics. PREROW (xw reload) runs AFTER the ii update (R5's bug
// was clobbering XW before use).

#define PGV(IS,N)  pg##IS##N
#define CNT(IS)    cnt##IS
#define FBV(IS)    fb##IS
#define REXV(IS,N) rex##IS##N

// extract next spike index s in ascending h = 4*l+q order; mutates m0..m3, comb
#define EXS(S) { int _l = __builtin_ctzll(comb); \
    unsigned _nib = (unsigned)((m0 >> _l) & 1ull) | (((unsigned)((m1 >> _l) & 1ull)) << 1) | \
                    (((unsigned)((m2 >> _l) & 1ull)) << 2) | (((unsigned)((m3 >> _l) & 1ull)) << 3); \
    int _q = (int)__builtin_ctz(_nib); \
    unsigned long long _bit = 1ull << _l; \
    m0 &= ~((_q == 0) ? _bit : 0ull); m1 &= ~((_q == 1) ? _bit : 0ull); \
    m2 &= ~((_q == 2) ? _bit : 0ull); m3 &= ~((_q == 3) ? _bit : 0ull); \
    comb = m0 | m1 | m2 | m3; \
    S = 4 * _l + _q; }

#define GROW(S) (*(const float4*)(w_recT + (size_t)(S) * HH + 4 * lane))

#define STEP(IS, AS, XW, PREROW) do {                                               \
    float vd0 = vv0 + am0 * (ii0 - vv0); float id0 = ii0 - bs0 * ii0;               \
    float vd1 = vv1 + am1 * (ii1 - vv1); float id1 = ii1 - bs1 * ii1;               \
    float vd2 = vv2 + am2 * (ii2 - vv2); float id2 = ii2 - bs2 * ii2;               \
    float vd3 = vv3 + am3 * (ii3 - vv3); float id3 = ii3 - bs3 * ii3;               \
    bool z0 = (vd0 - 1.0f) > 0.0f, z1 = (vd1 - 1.0f) > 0.0f;                        \
    bool z2 = (vd2 - 1.0f) > 0.0f, z3 = (vd3 - 1.0f) > 0.0f;                        \
    vv0 = z0 ? 0.0f : vd0; vv1 = z1 ? 0.0f : vd1;                                   \
    vv2 = z2 ? 0.0f : vd2; vv3 = z3 ? 0.0f : vd3;                                   \
    f4raw zf; zf.x = z0 ? 1.0f : 0.0f; zf.y = z1 ? 1.0f : 0.0f;                     \
    zf.z = z2 ? 1.0f : 0.0f; zf.w = z3 ? 1.0f : 0.0f;                               \
    unsigned long long m0 = __ballot(z0), m1 = __ballot(z1);                        \
    unsigned long long m2 = __ballot(z2), m3 = __ballot(z3);                        \
    unsigned long long comb = m0 | m1 | m2 | m3;                                    \
    CNT(IS) = __popcll(m0) + __popcll(m1) + __popcll(m2) + __popcll(m3);            \
    FBV(IS) = false;                                                                \
    if (CNT(IS) > 6) {                                                              \
        FBV(IS) = true;                                                             \
        float e0 = 0.f, e1 = 0.f, e2 = 0.f, e3 = 0.f;                               \
        while (comb) { int s; EXS(s); float4 e = GROW(s);                           \
            e0 += e.x; e1 += e.y; e2 += e.z; e3 += e.w; }                           \
        REXV(IS,0) = e0; REXV(IS,1) = e1; REXV(IS,2) = e2; REXV(IS,3) = e3;         \
    } else if (CNT(IS) > 0) {                                                       \
        int s;                                                                      \
        EXS(s); PGV(IS,0) = GROW(s);                                                \
        if (CNT(IS) > 1) { EXS(s); PGV(IS,1) = GROW(s);                             \
          if (CNT(IS) > 2) { EXS(s); PGV(IS,2) = GROW(s);                           \
            if (CNT(IS) > 3) { EXS(s); PGV(IS,3) = GROW(s);                         \
              if (CNT(IS) > 4) { EXS(s); PGV(IS,4) = GROW(s);                       \
                if (CNT(IS) > 5) { EXS(s); PGV(IS,5) = GROW(s); }}}}}               \
    }                                                                               \
    __builtin_nontemporal_store(zf, (f4raw*)(outp + stoff));                        \
    stoff += BH;                                                                    \
    zlast = zf;                                                                     \
    float r0, r1, r2, r3;                                                           \
    if (FBV(AS)) {                                                                  \
        r0 = REXV(AS,0); r1 = REXV(AS,1); r2 = REXV(AS,2); r3 = REXV(AS,3);         \
    } else {                                                                        \
        r0 = 0.f; r1 = 0.f; r2 = 0.f; r3 = 0.f;                                     \
        if (CNT(AS) > 0) { r0 += PGV(AS,0).x; r1 += PGV(AS,0).y;                    \
                           r2 += PGV(AS,0).z; r3 += PGV(AS,0).w;                    \
         if (CNT(AS) > 1) { r0 += PGV(AS,1).x; r1 += PGV(AS,1).y;                   \
                            r2 += PGV(AS,1).z; r3 += PGV(AS,1).w;                   \
          if (CNT(AS) > 2) { r0 += PGV(AS,2).x; r1 += PGV(AS,2).y;                  \
                             r2 += PGV(AS,2).z; r3 += PGV(AS,2).w;                  \
           if (CNT(AS) > 3) { r0 += PGV(AS,3).x; r1 += PGV(AS,3).y;                 \
                              r2 += PGV(AS,3).z; r3 += PGV(AS,3).w;                 \
            if (CNT(AS) > 4) { r0 += PGV(AS,4).x; r1 += PGV(AS,4).y;                \
                               r2 += PGV(AS,4).z; r3 += PGV(AS,4).w;                \
             if (CNT(AS) > 5) { r0 += PGV(AS,5).x; r1 += PGV(AS,5).y;               \
                                r2 += PGV(AS,5).z; r3 += PGV(AS,5).w; }}}}}}        \
    }                                                                               \
    ii0 = (id0 + (XW).x) + r0; ii1 = (id1 + (XW).y) + r1;                           \
    ii2 = (id2 + (XW).z) + r2; ii3 = (id3 + (XW).w) + r3;                           \
    PREROW;                                                                         \
} while (0)

__global__ __launch_bounds__(128) void scan_lif(const float* __restrict__ tau_syn,
                                                const float* __restrict__ tau_mem,
                                                const float* __restrict__ w_recT,
                                                float* __restrict__ outp) {
    const float DT = 0.001f;
    __shared__ __align__(16) float ring[2 * CH * HH];   // 32 KB: 2 slots x 16 rows x 1KB
    int b = blockIdx.x;
    int lane = threadIdx.x & 63;
    int wid = threadIdx.x >> 6;

    if (wid == 1) {
        // ---- producer: pre-stage chunk 0 into slot 0 ----
        float4 rb[CH];
#pragma unroll
        for (int r = 0; r < CH; ++r)
            rb[r] = *(const float4*)(outp + ((size_t)r * BB + b) * HH + 4 * lane);
#pragma unroll
        for (int r = 0; r < CH; ++r)
            *(float4*)&ring[r * HH + 4 * lane] = rb[r];
        __syncthreads();
        for (int c = 0; c < NCH; ++c) {
            if (c + 1 < NCH) {
                int t0 = (c + 1) * CH;
                int lb = ((c + 1) & 1) * (CH * HH);
                float4 sb[CH];
#pragma unroll
                for (int r = 0; r < CH; ++r)
                    sb[r] = *(const float4*)(outp + ((size_t)(t0 + r) * BB + b) * HH + 4 * lane);
#pragma unroll
                for (int r = 0; r < CH; ++r)
                    *(float4*)&ring[lb + r * HH + 4 * lane] = sb[r];
            }
            __syncthreads();
        }
        return;
    }

    // ---- consumer wave ----
    float4 tsv = *(const float4*)(tau_syn + 4 * lane);
    float4 tmv = *(const float4*)(tau_mem + 4 * lane);
    float am0 = DT * clip01(tmv.x), am1 = DT * clip01(tmv.y);
    float am2 = DT * clip01(tmv.z), am3 = DT * clip01(tmv.w);
    float bs0 = DT * clip01(tsv.x), bs1 = DT * clip01(tsv.y);
    float bs2 = DT * clip01(tsv.z), bs3 = DT * clip01(tsv.w);

    float vv0 = 0.f, vv1 = 0.f, vv2 = 0.f, vv3 = 0.f;
    float ii0 = 0.f, ii1 = 0.f, ii2 = 0.f, ii3 = 0.f;
    float4 pgA0 = {}, pgA1 = {}, pgA2 = {}, pgA3 = {}, pgA4 = {}, pgA5 = {};
    float4 pgB0 = {}, pgB1 = {}, pgB2 = {}, pgB3 = {}, pgB4 = {}, pgB5 = {};
    float rexA0 = 0.f, rexA1 = 0.f, rexA2 = 0.f, rexA3 = 0.f;
    float rexB0 = 0.f, rexB1 = 0.f, rexB2 = 0.f, rexB3 = 0.f;
    int cntA = 0, cntB = 0;
    bool fbA = false, fbB = false;
    f4raw zlast = {0.f, 0.f, 0.f, 0.f};
    unsigned stoff = (unsigned)(b * HH + 4 * lane);

    __syncthreads();   // chunk 0 staged

    for (int c = 0; c < NCH; ++c) {
        int lb = (c & 1) * (CH * HH);
        float4 xwA = *(const float4*)&ring[lb + 0 * HH + 4 * lane];
        float4 xwB = *(const float4*)&ring[lb + 1 * HH + 4 * lane];
        for (int u = 0; u < CH - 2; u += 2) {
            STEP(A, B, xwA, xwA = *(const float4*)&ring[lb + (u + 2) * HH + 4 * lane]);
            STEP(B, A, xwB, xwB = *(const float4*)&ring[lb + (u + 3) * HH + 4 * lane]);
        }
        STEP(A, B, xwA, ((void)0));
        STEP(B, A, xwB, ((void)0));
        __syncthreads();
    }

    // final state: z_f, v_f, i_f (all from registers)
    *(f4raw*)(outp + (size_t)TT * BH + b * HH + 4 * lane) = zlast;
    float4 vf = {vv0, vv1, vv2, vv3};
    float4 fi = {ii0, ii1, ii2, ii3};
    *(float4*)(outp + (size_t)TT * BH + BH + b * HH + 4 * lane) = vf;
    *(float4*)(outp + (size_t)TT * BH + 2 * BH + b * HH + 4 * lane) = fi;
}

extern "C" void kernel_launch(void* const* d_in, const int* in_sizes, int n_in,
                              void* d_out, int out_size, void* d_ws, size_t ws_size,
                              hipStream_t stream) {
    const float* x       = (const float*)d_in[0];
    const float* w_in    = (const float*)d_in[1];
    const float* w_rec   = (const float*)d_in[2];
    const float* tau_syn = (const float*)d_in[3];
    const float* tau_mem = (const float*)d_in[4];
    float* out = (float*)d_out;

    float* w_inT  = (float*)d_ws;           // 65536 floats
    float* w_recT = w_inT + HH * HH;        // 65536 floats

    transpose2<<<256, 256, 0, stream>>>(w_in, w_rec, w_inT, w_recT);

    dim3 ggrid((BB * TT) / BM, HH / BN);    // (1000, 2)
    gemm_xw<<<ggrid, 256, 0, stream>>>(x, w_inT, out);

    scan_lif<<<BB, 128, 0, stream>>>(tau_syn, tau_mem, w_recT, out);
}